// Round 6
// baseline (207.253 us; speedup 1.0000x reference)
//
#include <hip/hip_runtime.h>

// Embedding: out[t, :] = W[:, x[t]] + b   (W [256,100000] row-major f32)
//
// Round 6: split-E scatter. Evidence r2-r5: W reads at stride 400KB run at a
// ~3 TB/s wall for 64B AND 128B chunks (streaming = 6.8 TB/s) -> DRAM page
// efficiency, fixed only by >=1KB contiguous per row-visit. So each block now
// covers (256 vocab cols) x (64 embed rows): staging reads 1KB/row-visit, and
// a token's write is 256B contiguous (64 lanes x f32, nontemporal).
//   k0: zero bin counters (391 bins of 256 vocab cols)
//   k1: bucket tokens: bin = v>>8, entry = t | (c<<16)
//   k2: grid (391 bins x 4 e-groups): stage 64x256 tile to LDS (stride 257:
//       staging stores and column reads both conflict-free), then one wave
//       per token writes out[t][g*64 .. g*64+63] + bias.
//   k3: overflow cleanup (CAP=256 vs mean 168, ~7 sigma; never taken).

#define VOCAB 100000
#define EMBED 256
#define NTOK  (32 * 2048)
#define TILEC 256                 // vocab columns per bin (power of 2)
#define NBIN  ((VOCAB + TILEC - 1) / TILEC)   // 391 (last bin: 160 cols)
#define NEG   4                   // e-groups of 64 rows
#define CAP   256                 // slots per bin (mean 168)
#define LSTRIDE 257               // LDS row stride (odd -> conflict-free)

// workspace layout (ints): cnt [512) | list [NBIN*CAP) | flags [NTOK)
#define WS_CNT_OFF   0
#define WS_LIST_OFF  512
#define WS_FLAG_OFF  (WS_LIST_OFF + NBIN * CAP)
#define WS_INTS      (WS_FLAG_OFF + NTOK)

__global__ __launch_bounds__(256) void k0_zero(int* __restrict__ cnt)
{
    int i = blockIdx.x * 256 + threadIdx.x;
    if (i < NBIN) cnt[i] = 0;
}

__global__ __launch_bounds__(256) void k1_bucket(
    const int* __restrict__ x,
    int* __restrict__ cnt,
    int* __restrict__ list,
    int* __restrict__ flags)
{
    int t = blockIdx.x * 256 + threadIdx.x;
    if (t >= NTOK) return;
    int v   = x[t];
    int bin = v >> 8;                   // v / TILEC
    int c   = v & (TILEC - 1);
    int pos = atomicAdd(&cnt[bin], 1);
    int ovf = (pos >= CAP);
    if (!ovf) list[bin * CAP + pos] = t | (c << 16);   // t<65536, c<256
    flags[t] = ovf;                     // written for ALL t (ws is poisoned)
}

__global__ __launch_bounds__(256) void k2_scatter(
    const float* __restrict__ W,
    const float* __restrict__ bias,
    const int* __restrict__ cnt,
    const int* __restrict__ list,
    float* __restrict__ out)
{
    __shared__ float tileT[64 * LSTRIDE];   // [e_local][c]
    __shared__ int   slist[CAP];

    const int bin = blockIdx.x;
    const int g   = blockIdx.y;          // e-group: rows g*64 .. g*64+63
    const int v0  = bin << 8;
    const int cols = (VOCAB - v0 < TILEC) ? (VOCAB - v0) : TILEC;  // 256 or 160
    const int t   = threadIdx.x;
    const int lane = t & 63;
    const int wave = t >> 6;

    // prefetch this bin's token list (1 KB contiguous)
    slist[t] = list[bin * CAP + t];

    // stage 64 rows x `cols` floats. One wave covers one full row per pass:
    // 64 lanes x 16B = 1KB contiguous per row-visit (the DRAM-page fix).
    #pragma unroll
    for (int j = 0; j < 16; ++j) {
        const int r  = j * 4 + wave;     // 0..63
        const int c4 = lane << 2;        // 0..252
        if (c4 < cols) {
            const float4 w = *reinterpret_cast<const float4*>(
                W + (size_t)(g * 64 + r) * VOCAB + v0 + c4);
            tileT[r * LSTRIDE + c4 + 0] = w.x;
            tileT[r * LSTRIDE + c4 + 1] = w.y;
            tileT[r * LSTRIDE + c4 + 2] = w.z;
            tileT[r * LSTRIDE + c4 + 3] = w.w;
        }
    }
    __syncthreads();

    int n = cnt[bin];
    if (n > CAP) n = CAP;

    const float bv = bias[g * 64 + lane];

    // one wave per token: lane e_local=lane reads tile column c
    // (banks (lane+c)%32, 2-way across 64 lanes = free), writes 256B contiguous.
    for (int k = wave; k < n; k += 4) {
        const int packed = slist[k];
        const int tok = packed & 0xFFFF;
        const int c   = packed >> 16;
        const float val = tileT[lane * LSTRIDE + c] + bv;
        __builtin_nontemporal_store(val, out + (size_t)tok * EMBED + g * 64 + lane);
    }
}

__global__ __launch_bounds__(256) void k3_cleanup(
    const int* __restrict__ x,
    const float* __restrict__ W,
    const float* __restrict__ bias,
    const int* __restrict__ flags,
    float* __restrict__ out)
{
    int t = blockIdx.x * 256 + threadIdx.x;
    if (t >= NTOK) return;
    if (!flags[t]) return;              // never taken for this input
    int v = x[t];
    for (int e = 0; e < EMBED; ++e)
        out[(size_t)t * EMBED + e] = W[(size_t)e * VOCAB + v] + bias[e];
}

// fallback: direct column gather (round-2 kernel), if ws too small
__global__ __launch_bounds__(256) void embed_gather_direct(
    const int* __restrict__ x,
    const float* __restrict__ W,
    const float* __restrict__ bias,
    float* __restrict__ out)
{
    const int tid   = blockIdx.x * blockDim.x + threadIdx.x;
    const int token = tid >> 6;
    const int e     = (tid & 63) << 2;
    if (token >= NTOK) return;
    const int v = x[token];
    const float4 bv = *reinterpret_cast<const float4*>(bias + e);
    float4 r;
    r.x = W[(size_t)(e + 0) * VOCAB + v] + bv.x;
    r.y = W[(size_t)(e + 1) * VOCAB + v] + bv.y;
    r.z = W[(size_t)(e + 2) * VOCAB + v] + bv.z;
    r.w = W[(size_t)(e + 3) * VOCAB + v] + bv.w;
    *reinterpret_cast<float4*>(out + (size_t)token * EMBED + e) = r;
}

extern "C" void kernel_launch(void* const* d_in, const int* in_sizes, int n_in,
                              void* d_out, int out_size, void* d_ws, size_t ws_size,
                              hipStream_t stream)
{
    const int*   x = (const int*)d_in[0];
    const float* W = (const float*)d_in[1];
    const float* b = (const float*)d_in[2];
    float*     out = (float*)d_out;

    if (ws_size >= (size_t)WS_INTS * sizeof(int)) {
        int* ws    = (int*)d_ws;
        int* cnt   = ws + WS_CNT_OFF;
        int* list  = ws + WS_LIST_OFF;
        int* flags = ws + WS_FLAG_OFF;

        k0_zero   <<<(NBIN + 255) / 256, 256, 0, stream>>>(cnt);
        k1_bucket <<<NTOK / 256,         256, 0, stream>>>(x, cnt, list, flags);
        dim3 g2(NBIN, NEG);
        k2_scatter<<<g2,                 256, 0, stream>>>(W, b, cnt, list, out);
        k3_cleanup<<<NTOK / 256,         256, 0, stream>>>(x, W, b, flags, out);
    } else {
        embed_gather_direct<<<NTOK * 64 / 256, 256, 0, stream>>>(x, W, b, out);
    }
}